// Round 11
// baseline (100.648 us; speedup 1.0000x reference)
//
#include <hip/hip_runtime.h>
#include <stdint.h>

typedef __attribute__((ext_vector_type(8))) short s8v;
typedef __attribute__((ext_vector_type(4))) short s4v;
typedef __attribute__((ext_vector_type(4))) float f4v;
typedef __attribute__((ext_vector_type(16))) float f16v;

#define D_DIM 1024
#define H_NUM 16
#define HD 64
#define SEQ 2048
#define BSZ 2
#define MROWS (BSZ * SEQ)   // 4096
#define LOG2E 1.4426950408889634f

__device__ __forceinline__ unsigned short f2bf(float f) {
  unsigned u = __builtin_bit_cast(unsigned, f);
  u += 0x7fffu + ((u >> 16) & 1u);
  return (unsigned short)(u >> 16);
}

__device__ __forceinline__ float exp2q(float x) {
  float r;
  asm("v_exp_f32 %0, %1" : "=v"(r) : "v"(x));
  return r;
}

__device__ __forceinline__ float max3q(float a, float b, float c) {
  float r;
  asm("v_max3_f32 %0, %1, %2, %3" : "=v"(r) : "v"(a), "v"(b), "v"(c));
  return r;
}

__device__ __forceinline__ unsigned int cvtpk(float a, float b) {
  unsigned int r;
  asm("v_cvt_pk_bf16_f32 %0, %1, %2" : "=v"(r) : "v"(a), "v"(b));
  return r;
}

__device__ __forceinline__ void async16(const unsigned short* g, unsigned short* l) {
  __builtin_amdgcn_global_load_lds(
      (__attribute__((address_space(1))) unsigned int*)(uintptr_t)g,
      (__attribute__((address_space(3))) unsigned int*)l, 16, 0, 0);
}

__device__ __forceinline__ f4v mfma16(s8v a, s8v b, f4v c) {
  return __builtin_amdgcn_mfma_f32_16x16x32_bf16(a, b, c, 0, 0, 0);
}

__device__ __forceinline__ f16v mfma32(s8v a, s8v b, f16v c) {
  return __builtin_amdgcn_mfma_f32_32x32x16_bf16(a, b, c, 0, 0, 0);
}

__device__ __forceinline__ void barrier_raw() {
  __builtin_amdgcn_sched_barrier(0);
  __builtin_amdgcn_s_barrier();
  __builtin_amdgcn_sched_barrier(0);
}
#define WAITVM0() asm volatile("s_waitcnt vmcnt(0)" ::: "memory")
#define WAITVM4() asm volatile("s_waitcnt vmcnt(4)" ::: "memory")

// ---------------- fused fp32 -> bf16 convert (x, Wq, Wk, Wv) ----------------
__global__ __launch_bounds__(256) void cvt_all(
    const float* __restrict__ x, const float* __restrict__ Wq,
    const float* __restrict__ Wk, const float* __restrict__ Wv,
    unsigned short* __restrict__ Xb, unsigned short* __restrict__ Wb) {
  const int NX = MROWS * D_DIM / 4;
  const int NW = D_DIM * D_DIM / 4;
  int i = blockIdx.x * 256 + threadIdx.x;
  const float* src;
  unsigned short* dst;
  int off;
  if (i < NX) {
    src = x; dst = Xb; off = i;
  } else if (i < NX + NW) {
    src = Wq; dst = Wb; off = i - NX;
  } else if (i < NX + 2 * NW) {
    src = Wk; dst = Wb + D_DIM * D_DIM; off = i - NX - NW;
  } else {
    src = Wv; dst = Wb + 2 * D_DIM * D_DIM; off = i - NX - 2 * NW;
  }
  f4v v = *(const f4v*)(src + (size_t)off * 4);
  s4v o;
  o[0] = (short)f2bf(v[0]);
  o[1] = (short)f2bf(v[1]);
  o[2] = (short)f2bf(v[2]);
  o[3] = (short)f2bf(v[3]);
  *(s4v*)(dst + (size_t)off * 4) = o;
}

// ---------------- QKV projection GEMM: KSTEP=32, dbuf 2-phase, swizzled ----------------
__global__ __launch_bounds__(256) void qkv_gemm(
    const unsigned short* __restrict__ Xb, const unsigned short* __restrict__ Wb,
    const float* __restrict__ bq, const float* __restrict__ bk,
    const float* __restrict__ bv, unsigned short* __restrict__ qb,
    unsigned short* __restrict__ kb, unsigned short* __restrict__ vt) {
  __shared__ __align__(16) unsigned short At[2][128 * 32];
  __shared__ __align__(16) unsigned short Bt[2][128 * 32];

  const int z = blockIdx.z;
  const unsigned short* W = Wb + z * (D_DIM * D_DIM);
  const float* bias = (z == 0) ? bq : ((z == 1) ? bk : bv);
  const int row0 = blockIdx.x * 128;
  const int col0 = blockIdx.y * 128;
  const int t = threadIdx.x;
  const int w = t >> 6, l = t & 63;
  const int wr = w >> 1, wc = w & 1;
  const int lg = l >> 4, lc = l & 15;

  f4v acc[4][4];
#pragma unroll
  for (int m = 0; m < 4; ++m)
#pragma unroll
    for (int n = 0; n < 4; ++n) acc[m][n] = (f4v){0.f, 0.f, 0.f, 0.f};

  const int srow = t >> 2;
  const int sch = (t & 3) ^ ((t >> 3) & 3);
  const unsigned short* Asrc = Xb + (size_t)(row0 + srow) * D_DIM + sch * 8;
  const unsigned short* Bsrc = W + (size_t)(col0 + srow) * D_DIM + sch * 8;

  const int rch = lg ^ ((lc >> 1) & 3);
  const int arow = wr * 64 + lc;
  const int brow = wc * 64 + lc;

#define STAGE(b, k0)                                                        \
  do {                                                                      \
    async16(Asrc + (k0), At[b] + t * 8);                                    \
    async16(Asrc + (k0) + 64 * D_DIM, At[b] + 2048 + t * 8);                \
    async16(Bsrc + (k0), Bt[b] + t * 8);                                    \
    async16(Bsrc + (k0) + 64 * D_DIM, Bt[b] + 2048 + t * 8);                \
  } while (0)

  STAGE(0, 0);
  WAITVM0();
  barrier_raw();

  int cur = 0;
  for (int it = 0; it < 32; ++it) {
    if (it < 31) STAGE(cur ^ 1, (it + 1) * 32);
    s8v a[4], b[4];
#pragma unroll
    for (int m = 0; m < 4; ++m)
      a[m] = *(const s8v*)(At[cur] + (arow + m * 16) * 32 + rch * 8);
#pragma unroll
    for (int n = 0; n < 4; ++n)
      b[n] = *(const s8v*)(Bt[cur] + (brow + n * 16) * 32 + rch * 8);
    __builtin_amdgcn_s_setprio(1);
#pragma unroll
    for (int m = 0; m < 4; ++m)
#pragma unroll
      for (int n = 0; n < 4; ++n) acc[m][n] = mfma16(a[m], b[n], acc[m][n]);
    __builtin_amdgcn_s_setprio(0);
    WAITVM0();
    barrier_raw();
    cur ^= 1;
  }
#undef STAGE

  const float SCQ = 0.125f * LOG2E;
#pragma unroll
  for (int m = 0; m < 4; ++m) {
    const int sg0 = row0 + wr * 64 + m * 16 + 4 * lg;
    const int b = sg0 >> 11;
    const int sl0 = sg0 & (SEQ - 1);
#pragma unroll
    for (int n = 0; n < 4; ++n) {
      const int j = col0 + wc * 64 + n * 16 + lc;
      const int h = j >> 6, hd = j & 63;
      const float bs = bias[j];
      if (z == 2) {
        s4v o;
#pragma unroll
        for (int r = 0; r < 4; ++r) o[r] = (short)f2bf(acc[m][n][r] + bs);
        *(s4v*)(vt + ((size_t)(b * H_NUM + h) * HD + hd) * SEQ + sl0) = o;
      } else if (z == 0) {
#pragma unroll
        for (int r = 0; r < 4; ++r)
          qb[((size_t)(b * H_NUM + h) * SEQ + (sl0 + r)) * HD + hd] =
              f2bf((acc[m][n][r] + bs) * SCQ);
      } else {
#pragma unroll
        for (int r = 0; r < 4; ++r)
          kb[((size_t)(b * H_NUM + h) * SEQ + (sl0 + r)) * HD + hd] =
              f2bf(acc[m][n][r] + bs);
      }
    }
  }
}

// ---------------- flash attention v8: -m preloaded into QK accumulator ----------------
// 8 waves: waves 0-3 keys [0,1024), waves 4-7 keys [1024,2048), same 128 q-rows.
// minit = broadcast(-m) as QK C-input -> MFMA emits s-m directly (no sub pass).
// Defer-max: m starts 0, trigger iff any lane's tile-max' > 8 (constant compare).
// lsum on MFMA pipe (ones row); depth-2 counted vmcnt; conflict-free exchange.
__global__ __launch_bounds__(512, 4) void attn_fwd(
    const unsigned short* __restrict__ qb, const unsigned short* __restrict__ kb,
    const unsigned short* __restrict__ vt, const float* __restrict__ Bb,
    float* __restrict__ out) {
  __shared__ __align__(16) unsigned short Kl[2][2][64 * 64];   // [half][dbuf][key][d] 32KB
  __shared__ __align__(16) unsigned short Vl[2][2][64 * 64];   // [half][dbuf][d][key] 32KB

  const int bh = blockIdx.x;
  const int b = bh >> 4, h = bh & 15;
  const int q0 = blockIdx.y * 128;
  const int t = threadIdx.x, w = t >> 6, l = t & 63;
  const int ql = l & 31, hi = l >> 5;
  const int g = w >> 2;    // KV half
  const int pw = w & 3;    // q subtile
  (void)Bb;

  const unsigned short* Q = qb + (size_t)bh * SEQ * HD;
  const unsigned short* K = kb + (size_t)bh * SEQ * HD;
  const unsigned short* V = vt + (size_t)bh * HD * SEQ;

  // Q B-fragments: B[k=d = ks*16+8*hi+j][col=q=ql]
  const int qrow = q0 + pw * 32 + ql;
  const unsigned short* Qp = Q + (size_t)qrow * HD + 8 * hi;
  s8v qf[4];
#pragma unroll
  for (int ks = 0; ks < 4; ++ks) qf[ks] = *(const s8v*)(Qp + ks * 16);

  s8v ones;
#pragma unroll
  for (int i = 0; i < 8; ++i) ones[i] = (short)0x3F80;   // bf16 1.0

  f16v zf;
#pragma unroll
  for (int i = 0; i < 16; ++i) zf[i] = 0.f;
  f16v acc0 = zf, acc1 = zf, lacc = zf;
  f16v minit = zf;          // broadcast(-m); m starts at 0
  float m = 0.0f;           // running max (absolute, for cross-half combine)

  // LDS read offsets (shorts): row=ql (+32), chunk=(2ks+hi)^(ql&7)
  int off0[4], off1[4];
#pragma unroll
  for (int ks = 0; ks < 4; ++ks) {
    off0[ks] = ql * 64 + (((2 * ks + hi) ^ (ql & 7)) * 8);
    off1[ks] = off0[ks] + 2048;
  }

  // staging: per 256-thread group; 2 rounds each for K and V (rows srow, srow+32)
  const int tg = t & 255;
  const int srow = tg >> 3;
  const int sc8 = (tg & 7) ^ (srow & 7);
  const unsigned short* Kst = K + (size_t)(g * 1024 + srow) * HD + sc8 * 8;
  const unsigned short* Vst = V + (size_t)srow * SEQ + g * 1024 + sc8 * 8;
  unsigned short* Kd = &Kl[g][0][tg * 8];
  unsigned short* Vd = &Vl[g][0][tg * 8];
  const int ldsw = 64 * 64;

#define STAGE_KV(bsel)                                                      \
  do {                                                                      \
    async16(Kst, Kd + (bsel) * ldsw);                                       \
    async16(Kst + 32 * HD, Kd + (bsel) * ldsw + 2048);                      \
    async16(Vst, Vd + (bsel) * ldsw);                                       \
    async16(Vst + 32 * SEQ, Vd + (bsel) * ldsw + 2048);                     \
    Kst += 64 * HD;                                                         \
    Vst += 64;                                                              \
  } while (0)

  // depth-2 prologue: tiles 0 and 1 in flight
  STAGE_KV(0);
  STAGE_KV(1);

  for (int kt = 0; kt < 16; ++kt) {
    if (kt < 15) WAITVM4();   // tile kt landed; tile kt+1 stays in flight
    else WAITVM0();
    barrier_raw();

    const unsigned short* Kb_ = &Kl[g][kt & 1][0];
    const unsigned short* Vb_ = &Vl[g][kt & 1][0];

    // QK^T with C = -m: emits s' = s - m directly. keys 0-31 -> s0, 32-63 -> s1
    f16v s0, s1;
    __builtin_amdgcn_s_setprio(1);
    {
      s8v kf0 = *(const s8v*)(Kb_ + off0[0]);
      s8v kf1 = *(const s8v*)(Kb_ + off1[0]);
      s0 = mfma32(kf0, qf[0], minit);
      s1 = mfma32(kf1, qf[0], minit);
    }
#pragma unroll
    for (int ks = 1; ks < 4; ++ks) {
      s8v kf0 = *(const s8v*)(Kb_ + off0[ks]);
      s8v kf1 = *(const s8v*)(Kb_ + off1[ks]);
      s0 = mfma32(kf0, qf[ks], s0);
      s1 = mfma32(kf1, qf[ks], s1);
    }
    __builtin_amdgcn_s_setprio(0);

    // lane-local max of 32 (values already relative to m)
    float a0 = max3q(s0[0], s0[1], s0[2]);
    float a1 = max3q(s0[3], s0[4], s0[5]);
    float a2 = max3q(s0[6], s0[7], s0[8]);
    float a3 = max3q(s0[9], s0[10], s0[11]);
    float a4 = max3q(s0[12], s0[13], s0[14]);
    float a5 = max3q(s0[15], s1[0], s1[1]);
    float a6 = max3q(s1[2], s1[3], s1[4]);
    float a7 = max3q(s1[5], s1[6], s1[7]);
    float a8 = max3q(s1[8], s1[9], s1[10]);
    float a9 = max3q(s1[11], s1[12], s1[13]);
    float b0 = max3q(a0, a1, a2);
    float b1 = max3q(a3, a4, a5);
    float b2 = max3q(a6, a7, a8);
    float b3 = max3q(a9, s1[14], s1[15]);
    float tmax = fmaxf(fmaxf(b0, b1), fmaxf(b2, b3));

    if (!__all(tmax <= 8.0f)) {   // rare: some score exceeds m+8 -> advance m
      float tr = fmaxf(tmax, __shfl_xor(tmax, 32));   // > 8 > 0
      const float fs = exp2q(-tr);
      m += tr;
#pragma unroll
      for (int i = 0; i < 16; ++i) {
        acc0[i] *= fs;
        acc1[i] *= fs;
        minit[i] -= tr;
        s0[i] -= tr;
        s1[i] -= tr;
      }
      lacc[0] *= fs;
    }

    // p = exp2(s') directly
#pragma unroll
    for (int i = 0; i < 16; ++i) {
      s0[i] = exp2q(s0[i]);
      s1[i] = exp2q(s1[i]);
    }

    // pack P to bf16 pairs; build PV B-fragments in-register via permlane32_swap
    unsigned int u[16];
#pragma unroll
    for (int x = 0; x < 8; ++x) {
      u[x] = cvtpk(s0[2 * x], s0[2 * x + 1]);
      u[8 + x] = cvtpk(s1[2 * x], s1[2 * x + 1]);
    }
    s8v pb[4];
#pragma unroll
    for (int ks = 0; ks < 4; ++ks) {
      const int base = (ks >> 1) * 8 + (ks & 1) * 4;
      unsigned int x0 = u[base + 0], y0 = u[base + 2];
      unsigned int x1 = u[base + 1], y1 = u[base + 3];
      asm("v_permlane32_swap_b32 %0, %1" : "+v"(x0), "+v"(y0));
      asm("v_permlane32_swap_b32 %0, %1" : "+v"(x1), "+v"(y1));
      union { s8v v; unsigned int w[4]; } bb;
      bb.w[0] = x0; bb.w[1] = x1; bb.w[2] = y0; bb.w[3] = y1;
      pb[ks] = bb.v;
    }

    // PV: O^T[d][q] += V^T * P^T ; lsum rides the MFMA pipe via ones-row
    __builtin_amdgcn_s_setprio(1);
#pragma unroll
    for (int ks = 0; ks < 4; ++ks) {
      s8v vf0 = *(const s8v*)(Vb_ + off0[ks]);
      s8v vf1 = *(const s8v*)(Vb_ + off1[ks]);
      lacc = mfma32(ones, pb[ks], lacc);
      acc0 = mfma32(vf0, pb[ks], acc0);
      acc1 = mfma32(vf1, pb[ks], acc1);
    }
    __builtin_amdgcn_s_setprio(0);

    barrier_raw();                       // everyone done reading buf[kt&1]
    if (kt < 14) STAGE_KV(kt & 1);       // stage tile kt+2 into buf[kt&1]
  }
#undef STAGE_KV

  // lacc[0] = full rowsum over this half's keys for q=ql (same in both lane halves)
  const float lsum = lacc[0];

  // flash-combine across KV halves. Conflict-free exchange layout:
  // [plane][256 slots][4 floats] -> lane-consecutive 16B, no bank aliasing.
  float* exch = (float*)&Kl[0][0][0];   // 8 planes x 4 KB = 32 KB
  float* mlb = (float*)&Vl[0][0][0];    // m[128], l[128]
  const int slot = pw * 64 + l;

  __syncthreads();
  if (g == 1) {
#pragma unroll
    for (int gg = 0; gg < 4; ++gg) {
      f4v v0, v1;
#pragma unroll
      for (int r = 0; r < 4; ++r) { v0[r] = acc0[4 * gg + r]; v1[r] = acc1[4 * gg + r]; }
      *(f4v*)(exch + (gg * 256 + slot) * 4) = v0;
      *(f4v*)(exch + ((4 + gg) * 256 + slot) * 4) = v1;
    }
    if (hi == 0) {
      mlb[pw * 32 + ql] = m;
      mlb[128 + pw * 32 + ql] = lsum;
    }
  }
  __syncthreads();
  if (g == 0) {
    const float mb = mlb[pw * 32 + ql];
    const float lb = mlb[128 + pw * 32 + ql];
    const float ms = fmaxf(m, mb);
    const float fa = exp2q(m - ms);
    const float fb = exp2q(mb - ms);
    const float linv = 1.0f / (lsum * fa + lb * fb);
    const float sa = fa * linv, sb = fb * linv;
    const int q = q0 + pw * 32 + ql;
    float* op = out + ((size_t)(b * SEQ + q)) * D_DIM + h * 64;
#pragma unroll
    for (int gg = 0; gg < 4; ++gg) {
      f4v pa = *(const f4v*)(exch + (gg * 256 + slot) * 4);
      f4v pc = *(const f4v*)(exch + ((4 + gg) * 256 + slot) * 4);
      f4v o0, o1;
#pragma unroll
      for (int r = 0; r < 4; ++r) {
        o0[r] = acc0[4 * gg + r] * sa + pa[r] * sb;
        o1[r] = acc1[4 * gg + r] * sa + pc[r] * sb;
      }
      *(f4v*)(op + 8 * gg + 4 * hi) = o0;
      *(f4v*)(op + 32 + 8 * gg + 4 * hi) = o1;
    }
  }
}

extern "C" void kernel_launch(void* const* d_in, const int* in_sizes, int n_in,
                              void* d_out, int out_size, void* d_ws, size_t ws_size,
                              hipStream_t stream) {
  const float* x = (const float*)d_in[0];
  const float* Wq = (const float*)d_in[1];
  const float* bq = (const float*)d_in[2];
  const float* Wk = (const float*)d_in[3];
  const float* bk = (const float*)d_in[4];
  const float* Wv = (const float*)d_in[5];
  const float* bv = (const float*)d_in[6];
  const float* Bb = (const float*)d_in[7];
  float* out = (float*)d_out;

  char* ws = (char*)d_ws;
  unsigned short* Xb = (unsigned short*)ws;                          // 8 MiB
  unsigned short* Wb = (unsigned short*)(ws + (8ull << 20));         // 6 MiB
  unsigned short* qb = (unsigned short*)(ws + (14ull << 20));        // 8 MiB
  unsigned short* kb = (unsigned short*)(ws + (22ull << 20));        // 8 MiB
  unsigned short* vt = (unsigned short*)(ws + (30ull << 20));        // 8 MiB

  cvt_all<<<7168, 256, 0, stream>>>(x, Wq, Wk, Wv, Xb, Wb);

  dim3 ggrid(MROWS / 128, D_DIM / 128, 3);
  qkv_gemm<<<ggrid, 256, 0, stream>>>(Xb, Wb, bq, bk, bv, qb, kb, vt);

  dim3 agrid(BSZ * H_NUM, SEQ / 128);
  attn_fwd<<<agrid, 512, 0, stream>>>(qb, kb, vt, Bb, out);
}

// Round 12
// 92.865 us; speedup vs baseline: 1.0838x; 1.0838x over previous
//
#include <hip/hip_runtime.h>
#include <stdint.h>

typedef __attribute__((ext_vector_type(8))) short s8v;
typedef __attribute__((ext_vector_type(4))) short s4v;
typedef __attribute__((ext_vector_type(4))) float f4v;
typedef __attribute__((ext_vector_type(16))) float f16v;

#define D_DIM 1024
#define H_NUM 16
#define HD 64
#define SEQ 2048
#define BSZ 2
#define MROWS (BSZ * SEQ)   // 4096
#define LOG2E 1.4426950408889634f

__device__ __forceinline__ unsigned short f2bf(float f) {
  unsigned u = __builtin_bit_cast(unsigned, f);
  u += 0x7fffu + ((u >> 16) & 1u);
  return (unsigned short)(u >> 16);
}

__device__ __forceinline__ float exp2q(float x) {
  float r;
  asm("v_exp_f32 %0, %1" : "=v"(r) : "v"(x));
  return r;
}

__device__ __forceinline__ float max3q(float a, float b, float c) {
  float r;
  asm("v_max3_f32 %0, %1, %2, %3" : "=v"(r) : "v"(a), "v"(b), "v"(c));
  return r;
}

__device__ __forceinline__ unsigned int cvtpk(float a, float b) {
  unsigned int r;
  asm("v_cvt_pk_bf16_f32 %0, %1, %2" : "=v"(r) : "v"(a), "v"(b));
  return r;
}

__device__ __forceinline__ void async16(const unsigned short* g, unsigned short* l) {
  __builtin_amdgcn_global_load_lds(
      (__attribute__((address_space(1))) unsigned int*)(uintptr_t)g,
      (__attribute__((address_space(3))) unsigned int*)l, 16, 0, 0);
}

__device__ __forceinline__ f4v mfma16(s8v a, s8v b, f4v c) {
  return __builtin_amdgcn_mfma_f32_16x16x32_bf16(a, b, c, 0, 0, 0);
}

__device__ __forceinline__ f16v mfma32(s8v a, s8v b, f16v c) {
  return __builtin_amdgcn_mfma_f32_32x32x16_bf16(a, b, c, 0, 0, 0);
}

__device__ __forceinline__ void barrier_raw() {
  __builtin_amdgcn_sched_barrier(0);
  __builtin_amdgcn_s_barrier();
  __builtin_amdgcn_sched_barrier(0);
}
#define WAITVM0() asm volatile("s_waitcnt vmcnt(0)" ::: "memory")
#define WAITVM4() asm volatile("s_waitcnt vmcnt(4)" ::: "memory")

// ---------------- fused fp32 -> bf16 convert: 8 floats/thread, 16B stores ----------------
__global__ __launch_bounds__(256) void cvt_all(
    const float* __restrict__ x, const float* __restrict__ Wq,
    const float* __restrict__ Wk, const float* __restrict__ Wv,
    unsigned short* __restrict__ Xb, unsigned short* __restrict__ Wb) {
  const int NX8 = MROWS * D_DIM / 8;   // 524288 chunks of 8
  const int NW8 = D_DIM * D_DIM / 8;   // 131072 per W
  int i = blockIdx.x * 256 + threadIdx.x;
  const float* src;
  unsigned short* dst;
  int off;
  if (i < NX8) {
    src = x; dst = Xb; off = i;
  } else if (i < NX8 + NW8) {
    src = Wq; dst = Wb; off = i - NX8;
  } else if (i < NX8 + 2 * NW8) {
    src = Wk; dst = Wb + D_DIM * D_DIM; off = i - NX8 - NW8;
  } else {
    src = Wv; dst = Wb + 2 * D_DIM * D_DIM; off = i - NX8 - 2 * NW8;
  }
  f4v v0 = *(const f4v*)(src + (size_t)off * 8);
  f4v v1 = *(const f4v*)(src + (size_t)off * 8 + 4);
  s8v o;
  o[0] = (short)f2bf(v0[0]);
  o[1] = (short)f2bf(v0[1]);
  o[2] = (short)f2bf(v0[2]);
  o[3] = (short)f2bf(v0[3]);
  o[4] = (short)f2bf(v1[0]);
  o[5] = (short)f2bf(v1[1]);
  o[6] = (short)f2bf(v1[2]);
  o[7] = (short)f2bf(v1[3]);
  *(s8v*)(dst + (size_t)off * 8) = o;
}

// ---------------- QKV projection GEMM: KSTEP=32, dbuf 2-phase, swizzled ----------------
__global__ __launch_bounds__(256) void qkv_gemm(
    const unsigned short* __restrict__ Xb, const unsigned short* __restrict__ Wb,
    const float* __restrict__ bq, const float* __restrict__ bk,
    const float* __restrict__ bv, unsigned short* __restrict__ qb,
    unsigned short* __restrict__ kb, unsigned short* __restrict__ vt) {
  __shared__ __align__(16) unsigned short At[2][128 * 32];
  __shared__ __align__(16) unsigned short Bt[2][128 * 32];

  const int z = blockIdx.z;
  const unsigned short* W = Wb + z * (D_DIM * D_DIM);
  const float* bias = (z == 0) ? bq : ((z == 1) ? bk : bv);
  const int row0 = blockIdx.x * 128;
  const int col0 = blockIdx.y * 128;
  const int t = threadIdx.x;
  const int w = t >> 6, l = t & 63;
  const int wr = w >> 1, wc = w & 1;
  const int lg = l >> 4, lc = l & 15;

  f4v acc[4][4];
#pragma unroll
  for (int m = 0; m < 4; ++m)
#pragma unroll
    for (int n = 0; n < 4; ++n) acc[m][n] = (f4v){0.f, 0.f, 0.f, 0.f};

  const int srow = t >> 2;
  const int sch = (t & 3) ^ ((t >> 3) & 3);
  const unsigned short* Asrc = Xb + (size_t)(row0 + srow) * D_DIM + sch * 8;
  const unsigned short* Bsrc = W + (size_t)(col0 + srow) * D_DIM + sch * 8;

  const int rch = lg ^ ((lc >> 1) & 3);
  const int arow = wr * 64 + lc;
  const int brow = wc * 64 + lc;

#define STAGE(b, k0)                                                        \
  do {                                                                      \
    async16(Asrc + (k0), At[b] + t * 8);                                    \
    async16(Asrc + (k0) + 64 * D_DIM, At[b] + 2048 + t * 8);                \
    async16(Bsrc + (k0), Bt[b] + t * 8);                                    \
    async16(Bsrc + (k0) + 64 * D_DIM, Bt[b] + 2048 + t * 8);                \
  } while (0)

  STAGE(0, 0);
  WAITVM0();
  barrier_raw();

  int cur = 0;
  for (int it = 0; it < 32; ++it) {
    if (it < 31) STAGE(cur ^ 1, (it + 1) * 32);
    s8v a[4], b[4];
#pragma unroll
    for (int m = 0; m < 4; ++m)
      a[m] = *(const s8v*)(At[cur] + (arow + m * 16) * 32 + rch * 8);
#pragma unroll
    for (int n = 0; n < 4; ++n)
      b[n] = *(const s8v*)(Bt[cur] + (brow + n * 16) * 32 + rch * 8);
    __builtin_amdgcn_s_setprio(1);
#pragma unroll
    for (int m = 0; m < 4; ++m)
#pragma unroll
      for (int n = 0; n < 4; ++n) acc[m][n] = mfma16(a[m], b[n], acc[m][n]);
    __builtin_amdgcn_s_setprio(0);
    WAITVM0();
    barrier_raw();
    cur ^= 1;
  }
#undef STAGE

  const float SCQ = 0.125f * LOG2E;
#pragma unroll
  for (int m = 0; m < 4; ++m) {
    const int sg0 = row0 + wr * 64 + m * 16 + 4 * lg;
    const int b = sg0 >> 11;
    const int sl0 = sg0 & (SEQ - 1);
#pragma unroll
    for (int n = 0; n < 4; ++n) {
      const int j = col0 + wc * 64 + n * 16 + lc;
      const int h = j >> 6, hd = j & 63;
      const float bs = bias[j];
      if (z == 2) {
        s4v o;
#pragma unroll
        for (int r = 0; r < 4; ++r) o[r] = (short)f2bf(acc[m][n][r] + bs);
        *(s4v*)(vt + ((size_t)(b * H_NUM + h) * HD + hd) * SEQ + sl0) = o;
      } else if (z == 0) {
#pragma unroll
        for (int r = 0; r < 4; ++r)
          qb[((size_t)(b * H_NUM + h) * SEQ + (sl0 + r)) * HD + hd] =
              f2bf((acc[m][n][r] + bs) * SCQ);
      } else {
#pragma unroll
        for (int r = 0; r < 4; ++r)
          kb[((size_t)(b * H_NUM + h) * SEQ + (sl0 + r)) * HD + hd] =
              f2bf(acc[m][n][r] + bs);
      }
    }
  }
}

// ---------------- flash attention v7 (r10 exact): ones-MFMA lsum, defer-max ----------------
__global__ __launch_bounds__(512, 4) void attn_fwd(
    const unsigned short* __restrict__ qb, const unsigned short* __restrict__ kb,
    const unsigned short* __restrict__ vt, const float* __restrict__ Bb,
    float* __restrict__ out) {
  __shared__ __align__(16) unsigned short Kl[2][2][64 * 64];   // [half][dbuf][key][d] 32KB
  __shared__ __align__(16) unsigned short Vl[2][2][64 * 64];   // [half][dbuf][d][key] 32KB

  const int bh = blockIdx.x;
  const int b = bh >> 4, h = bh & 15;
  const int q0 = blockIdx.y * 128;
  const int t = threadIdx.x, w = t >> 6, l = t & 63;
  const int ql = l & 31, hi = l >> 5;
  const int g = w >> 2;    // KV half
  const int pw = w & 3;    // q subtile
  (void)Bb;

  const unsigned short* Q = qb + (size_t)bh * SEQ * HD;
  const unsigned short* K = kb + (size_t)bh * SEQ * HD;
  const unsigned short* V = vt + (size_t)bh * HD * SEQ;

  // Q B-fragments: B[k=d = ks*16+8*hi+j][col=q=ql]
  const int qrow = q0 + pw * 32 + ql;
  const unsigned short* Qp = Q + (size_t)qrow * HD + 8 * hi;
  s8v qf[4];
#pragma unroll
  for (int ks = 0; ks < 4; ++ks) qf[ks] = *(const s8v*)(Qp + ks * 16);

  s8v ones;
#pragma unroll
  for (int i = 0; i < 8; ++i) ones[i] = (short)0x3F80;   // bf16 1.0

  f16v zf;
#pragma unroll
  for (int i = 0; i < 16; ++i) zf[i] = 0.f;
  f16v acc0 = zf, acc1 = zf, lacc = zf;
  float m = -3.0e38f, thr = -3.0e38f;

  // LDS read offsets (shorts): row=ql (+32), chunk=(2ks+hi)^(ql&7)
  int off0[4], off1[4];
#pragma unroll
  for (int ks = 0; ks < 4; ++ks) {
    off0[ks] = ql * 64 + (((2 * ks + hi) ^ (ql & 7)) * 8);
    off1[ks] = off0[ks] + 2048;
  }

  // staging: per 256-thread group; 2 rounds each for K and V (rows srow, srow+32)
  const int tg = t & 255;
  const int srow = tg >> 3;
  const int sc8 = (tg & 7) ^ (srow & 7);
  const unsigned short* Kst = K + (size_t)(g * 1024 + srow) * HD + sc8 * 8;
  const unsigned short* Vst = V + (size_t)srow * SEQ + g * 1024 + sc8 * 8;
  unsigned short* Kd = &Kl[g][0][tg * 8];
  unsigned short* Vd = &Vl[g][0][tg * 8];
  const int ldsw = 64 * 64;

#define STAGE_KV(bsel)                                                      \
  do {                                                                      \
    async16(Kst, Kd + (bsel) * ldsw);                                       \
    async16(Kst + 32 * HD, Kd + (bsel) * ldsw + 2048);                      \
    async16(Vst, Vd + (bsel) * ldsw);                                       \
    async16(Vst + 32 * SEQ, Vd + (bsel) * ldsw + 2048);                     \
    Kst += 64 * HD;                                                         \
    Vst += 64;                                                              \
  } while (0)

  // depth-2 prologue: tiles 0 and 1 in flight
  STAGE_KV(0);
  STAGE_KV(1);

  for (int kt = 0; kt < 16; ++kt) {
    if (kt < 15) WAITVM4();   // tile kt landed; tile kt+1 stays in flight
    else WAITVM0();
    barrier_raw();

    const unsigned short* Kb_ = &Kl[g][kt & 1][0];
    const unsigned short* Vb_ = &Vl[g][kt & 1][0];

    // QK^T: S^T[key][q], keys 0-31 -> s0, 32-63 -> s1 (log2-domain scores)
    f16v s0, s1;
    __builtin_amdgcn_s_setprio(1);
    {
      s8v kf0 = *(const s8v*)(Kb_ + off0[0]);
      s8v kf1 = *(const s8v*)(Kb_ + off1[0]);
      s0 = mfma32(kf0, qf[0], zf);
      s1 = mfma32(kf1, qf[0], zf);
    }
#pragma unroll
    for (int ks = 1; ks < 4; ++ks) {
      s8v kf0 = *(const s8v*)(Kb_ + off0[ks]);
      s8v kf1 = *(const s8v*)(Kb_ + off1[ks]);
      s0 = mfma32(kf0, qf[ks], s0);
      s1 = mfma32(kf1, qf[ks], s1);
    }
    __builtin_amdgcn_s_setprio(0);

    // lane-local max of 32 via max3 tree
    float a0 = max3q(s0[0], s0[1], s0[2]);
    float a1 = max3q(s0[3], s0[4], s0[5]);
    float a2 = max3q(s0[6], s0[7], s0[8]);
    float a3 = max3q(s0[9], s0[10], s0[11]);
    float a4 = max3q(s0[12], s0[13], s0[14]);
    float a5 = max3q(s0[15], s1[0], s1[1]);
    float a6 = max3q(s1[2], s1[3], s1[4]);
    float a7 = max3q(s1[5], s1[6], s1[7]);
    float a8 = max3q(s1[8], s1[9], s1[10]);
    float a9 = max3q(s1[11], s1[12], s1[13]);
    float b0 = max3q(a0, a1, a2);
    float b1 = max3q(a3, a4, a5);
    float b2 = max3q(a6, a7, a8);
    float b3 = max3q(a9, s1[14], s1[15]);
    float tmax = fmaxf(fmaxf(b0, b1), fmaxf(b2, b3));

    if (!__all(tmax <= thr)) {   // rare after warmup: reduce over lane pair + rescale
      float tr = fmaxf(tmax, __shfl_xor(tmax, 32));
      const float mn = fmaxf(m, tr);
      const float fs = exp2q(m - mn);
      m = mn;
      thr = mn + 8.0f;
#pragma unroll
      for (int i = 0; i < 16; ++i) { acc0[i] *= fs; acc1[i] *= fs; }
      lacc[0] *= fs;   // only row 0 is read; rows evolve independently in MFMA
    }

    // p = exp2(s - m)
#pragma unroll
    for (int i = 0; i < 16; ++i) {
      s0[i] = exp2q(s0[i] - m);
      s1[i] = exp2q(s1[i] - m);
    }

    // pack P to bf16 pairs; build PV B-fragments in-register via permlane32_swap
    unsigned int u[16];
#pragma unroll
    for (int x = 0; x < 8; ++x) {
      u[x] = cvtpk(s0[2 * x], s0[2 * x + 1]);
      u[8 + x] = cvtpk(s1[2 * x], s1[2 * x + 1]);
    }
    s8v pb[4];
#pragma unroll
    for (int ks = 0; ks < 4; ++ks) {
      const int base = (ks >> 1) * 8 + (ks & 1) * 4;
      unsigned int x0 = u[base + 0], y0 = u[base + 2];
      unsigned int x1 = u[base + 1], y1 = u[base + 3];
      asm("v_permlane32_swap_b32 %0, %1" : "+v"(x0), "+v"(y0));
      asm("v_permlane32_swap_b32 %0, %1" : "+v"(x1), "+v"(y1));
      union { s8v v; unsigned int w[4]; } bb;
      bb.w[0] = x0; bb.w[1] = x1; bb.w[2] = y0; bb.w[3] = y1;
      pb[ks] = bb.v;
    }

    // PV: O^T[d][q] += V^T * P^T ; lsum rides the MFMA pipe via ones-row
    __builtin_amdgcn_s_setprio(1);
#pragma unroll
    for (int ks = 0; ks < 4; ++ks) {
      s8v vf0 = *(const s8v*)(Vb_ + off0[ks]);
      s8v vf1 = *(const s8v*)(Vb_ + off1[ks]);
      lacc = mfma32(ones, pb[ks], lacc);
      acc0 = mfma32(vf0, pb[ks], acc0);
      acc1 = mfma32(vf1, pb[ks], acc1);
    }
    __builtin_amdgcn_s_setprio(0);

    barrier_raw();                       // everyone done reading buf[kt&1]
    if (kt < 14) STAGE_KV(kt & 1);       // stage tile kt+2 into buf[kt&1]
  }
#undef STAGE_KV

  // lacc[0] = full rowsum over this half's keys for q=ql (same in both lane halves)
  const float lsum = lacc[0];

  // flash-combine across KV halves. Conflict-free exchange layout:
  // [plane][256 slots][4 floats] -> lane-consecutive 16B, no bank aliasing.
  float* exch = (float*)&Kl[0][0][0];   // 8 planes x 4 KB = 32 KB
  float* mlb = (float*)&Vl[0][0][0];    // m[128], l[128]
  const int slot = pw * 64 + l;

  __syncthreads();
  if (g == 1) {
#pragma unroll
    for (int gg = 0; gg < 4; ++gg) {
      f4v v0, v1;
#pragma unroll
      for (int r = 0; r < 4; ++r) { v0[r] = acc0[4 * gg + r]; v1[r] = acc1[4 * gg + r]; }
      *(f4v*)(exch + (gg * 256 + slot) * 4) = v0;
      *(f4v*)(exch + ((4 + gg) * 256 + slot) * 4) = v1;
    }
    if (hi == 0) {
      mlb[pw * 32 + ql] = m;
      mlb[128 + pw * 32 + ql] = lsum;
    }
  }
  __syncthreads();
  if (g == 0) {
    const float mb = mlb[pw * 32 + ql];
    const float lb = mlb[128 + pw * 32 + ql];
    const float ms = fmaxf(m, mb);
    const float fa = exp2q(m - ms);
    const float fb = exp2q(mb - ms);
    const float linv = 1.0f / (lsum * fa + lb * fb);
    const float sa = fa * linv, sb = fb * linv;
    const int q = q0 + pw * 32 + ql;
    float* op = out + ((size_t)(b * SEQ + q)) * D_DIM + h * 64;
#pragma unroll
    for (int gg = 0; gg < 4; ++gg) {
      f4v pa = *(const f4v*)(exch + (gg * 256 + slot) * 4);
      f4v pc = *(const f4v*)(exch + ((4 + gg) * 256 + slot) * 4);
      f4v o0, o1;
#pragma unroll
      for (int r = 0; r < 4; ++r) {
        o0[r] = acc0[4 * gg + r] * sa + pa[r] * sb;
        o1[r] = acc1[4 * gg + r] * sa + pc[r] * sb;
      }
      *(f4v*)(op + 8 * gg + 4 * hi) = o0;
      *(f4v*)(op + 32 + 8 * gg + 4 * hi) = o1;
    }
  }
}

extern "C" void kernel_launch(void* const* d_in, const int* in_sizes, int n_in,
                              void* d_out, int out_size, void* d_ws, size_t ws_size,
                              hipStream_t stream) {
  const float* x = (const float*)d_in[0];
  const float* Wq = (const float*)d_in[1];
  const float* bq = (const float*)d_in[2];
  const float* Wk = (const float*)d_in[3];
  const float* bk = (const float*)d_in[4];
  const float* Wv = (const float*)d_in[5];
  const float* bv = (const float*)d_in[6];
  const float* Bb = (const float*)d_in[7];
  float* out = (float*)d_out;

  char* ws = (char*)d_ws;
  unsigned short* Xb = (unsigned short*)ws;                          // 8 MiB
  unsigned short* Wb = (unsigned short*)(ws + (8ull << 20));         // 6 MiB
  unsigned short* qb = (unsigned short*)(ws + (14ull << 20));        // 8 MiB
  unsigned short* kb = (unsigned short*)(ws + (22ull << 20));        // 8 MiB
  unsigned short* vt = (unsigned short*)(ws + (30ull << 20));        // 8 MiB

  // 8 floats/thread: (NX8 + 3*NW8) / 256 = 3584 blocks, exact cover
  cvt_all<<<3584, 256, 0, stream>>>(x, Wq, Wk, Wv, Xb, Wb);

  dim3 ggrid(MROWS / 128, D_DIM / 128, 3);
  qkv_gemm<<<ggrid, 256, 0, stream>>>(Xb, Wb, bq, bk, bv, qb, kb, vt);

  dim3 agrid(BSZ * H_NUM, SEQ / 128);
  attn_fwd<<<agrid, 512, 0, stream>>>(qb, kb, vt, Bb, out);
}